// Round 10
// baseline (453.450 us; speedup 1.0000x reference)
//
#include <hip/hip_runtime.h>

#define HDIM 128

typedef unsigned int uint;
typedef unsigned short ushort;
typedef __attribute__((ext_vector_type(8))) short short8;
typedef __attribute__((ext_vector_type(4))) float f32x4;

typedef __attribute__((address_space(3))) uint  lds_u32_t;
typedef const __attribute__((address_space(1))) uint g_u32_t;
#define GLDS16(gp, lp) __builtin_amdgcn_global_load_lds((g_u32_t*)(gp), (lds_u32_t*)(lp), 16, 0, 0)

// round-to-nearest-even float -> bf16 bits
__device__ inline ushort f2bf(float f) {
    uint u = __float_as_uint(f);
    uint rounding = 0x7fffu + ((u >> 16) & 1u);
    return (ushort)((u + rounding) >> 16);
}
__device__ inline float bf2f(ushort h) { return __uint_as_float(((uint)h) << 16); }

__device__ inline float4 bf4_to_f4(uint2 u) {
    float4 r;
    r.x = __uint_as_float(u.x << 16);
    r.y = __uint_as_float(u.x & 0xffff0000u);
    r.z = __uint_as_float(u.y << 16);
    r.w = __uint_as_float(u.y & 0xffff0000u);
    return r;
}

// ======================= CSR build =======================

__global__ __launch_bounds__(256) void k_count(const int* __restrict__ dst,
                                               int* __restrict__ cnt,
                                               int* __restrict__ rank, int e) {
    int i = blockIdx.x * 256 + threadIdx.x;
    if (i < e) rank[i] = atomicAdd(&cnt[dst[i]], 1);
}

__global__ __launch_bounds__(256) void k_dinv(const int* __restrict__ cnt,
                                              float* __restrict__ dinv, int n) {
    int i = blockIdx.x * 256 + threadIdx.x;
    if (i < n) dinv[i] = rsqrtf((float)(cnt[i] + 1));   // +1 self-loop
}

__global__ __launch_bounds__(256) void k_scan1(const int* __restrict__ cnt,
                                               int* __restrict__ offs,
                                               int* __restrict__ bsum, int n) {
    __shared__ int sm[256];
    int tid = threadIdx.x;
    int i = blockIdx.x * 256 + tid;
    int v = (i < n) ? cnt[i] : 0;
    sm[tid] = v;
    __syncthreads();
    for (int off = 1; off < 256; off <<= 1) {
        int t = (tid >= off) ? sm[tid - off] : 0;
        __syncthreads();
        sm[tid] += t;
        __syncthreads();
    }
    if (i < n) offs[i] = sm[tid] - v;
    if (tid == 255) bsum[blockIdx.x] = sm[255];
}

__global__ __launch_bounds__(512) void k_scan2(int* __restrict__ bsum, int nb) {
    __shared__ int sm[512];
    int tid = threadIdx.x;
    int v = (tid < nb) ? bsum[tid] : 0;
    sm[tid] = v;
    __syncthreads();
    for (int off = 1; off < 512; off <<= 1) {
        int t = (tid >= off) ? sm[tid - off] : 0;
        __syncthreads();
        sm[tid] += t;
        __syncthreads();
    }
    if (tid < nb) bsum[tid] = sm[tid] - v;
}

__global__ __launch_bounds__(256) void k_scan3(int* __restrict__ offs,
                                               const int* __restrict__ bsum,
                                               int n, int e) {
    int i = blockIdx.x * 256 + threadIdx.x;
    if (i < n) offs[i] += bsum[blockIdx.x];
    if (i == 0) offs[n] = e;
}

__global__ __launch_bounds__(256) void k_fill(const int* __restrict__ src,
                                              const int* __restrict__ dst,
                                              const int* __restrict__ offs,
                                              const int* __restrict__ rank,
                                              int* __restrict__ csr, int e) {
    int i = blockIdx.x * 256 + threadIdx.x;
    if (i < e) {
        csr[offs[dst[i]] + rank[i]] = src[i];
    }
}

// ===== W prep: transpose W[K][128] -> tile-major swizzled bf16 plane [K/32][128][32] =====
// 8-ushort unit of row c: physical = logical ^ ((c>>1)&3).

__global__ __launch_bounds__(256) void k_prep_w(const float* __restrict__ W,
                                                ushort* __restrict__ wt, int K) {
    int idx = blockIdx.x * 256 + threadIdx.x;
    if (idx < K * HDIM) {
        int k = idx >> 7;       // k index (row in W)
        int c = idx & 127;      // output col
        int pos = (k >> 5) * 4096 + c * 32 + ((k & 31) ^ (((c >> 1) & 3) << 3));
        wt[pos] = f2bf(W[idx]);
    }
}

// ===== X split: x fp32 [n][256] -> tile-major swizzled bf16 plane [8][n][32] =====
// grid: (n*4 units / 256, 8 kt). Thread handles one 8-ushort unit.

__global__ __launch_bounds__(256) void k_split_x(const float* __restrict__ X,
                                                 ushort* __restrict__ XP, int n) {
    int u  = blockIdx.x * 256 + threadIdx.x;   // node*4 + p
    int kt = blockIdx.y;
    if (u >= n * 4) return;
    int node = u >> 2;
    int p    = u & 3;
    int lu   = p ^ ((node >> 1) & 3);
    const float* xs = X + (size_t)node * 256 + kt * 32 + lu * 8;
    float4 a = *(const float4*)xs;
    float4 b = *(const float4*)(xs + 4);
    uint2 pk;
    pk.x = (uint)f2bf(a.x) | ((uint)f2bf(a.y) << 16);
    pk.y = (uint)f2bf(a.z) | ((uint)f2bf(a.w) << 16);
    uint2 pk2;
    pk2.x = (uint)f2bf(b.x) | ((uint)f2bf(b.y) << 16);
    pk2.y = (uint)f2bf(b.z) | ((uint)f2bf(b.w) << 16);
    uint4 o = make_uint4(pk.x, pk.y, pk2.x, pk2.y);
    *(uint4*)(XP + (size_t)kt * n * 32 + (size_t)node * 32 + p * 8) = o;
}

// =============== MFMA GEMM: g = bf16( dinv .* (X @ W) ), pure bf16 ===============
// W plane staged to LDS once per block (single barrier); waves then free-run a
// multi-tile loop (16 rows/tile) with depth-1 X prefetch; X read as coalesced
// 1KB wave-loads from the tile-major plane. No inner barriers.

template<int NKT>   // K = NKT*32
__global__ __launch_bounds__(512, 2)
void k_mm(const ushort* __restrict__ XP,
          const ushort* __restrict__ WP,
          const float* __restrict__ dinv,
          ushort* __restrict__ g, int n, int nblocks)
{
    __shared__ ushort w[NKT][128][32];    // 8KB per kt (pre-swizzled)

    const int tid  = threadIdx.x;
    const int wv   = tid >> 6;
    const int lane = tid & 63;
    const int r    = lane & 15;
    const int gq   = lane >> 4;
    const int pu8  = (gq ^ ((r >> 1) & 3)) * 8;   // swizzled 8-ushort unit offset

    // stage W (linear copy of pre-swizzled plane)
    {
        constexpr int CH = NKT * 4096 / (512 * 8);
        #pragma unroll
        for (int i = 0; i < CH; i++) {
            int off = (i * 512 + tid) * 8;
            GLDS16(WP + off, ((ushort*)w) + off);
        }
    }

    const int ntiles = (n + 15) / 16;
    const size_t n32 = (size_t)n * 32;
    const int tstep  = nblocks * 8;
    int tile = blockIdx.x * 8 + wv;

    short8 xc[NKT], xn[NKT];
    if (tile < ntiles) {
        int rowr = tile * 16 + r; if (rowr >= n) rowr = 0;
        size_t ro = (size_t)rowr * 32 + pu8;
        #pragma unroll
        for (int kt = 0; kt < NKT; kt++)
            xc[kt] = *(const short8*)(XP + kt * n32 + ro);
    }

    __syncthreads();   // W resident (drains glds + first X prefetch)

    while (tile < ntiles) {
        int tnext = tile + tstep;
        if (tnext < ntiles) {
            int rn = tnext * 16 + r; if (rn >= n) rn = 0;
            size_t ro2 = (size_t)rn * 32 + pu8;
            #pragma unroll
            for (int kt = 0; kt < NKT; kt++)
                xn[kt] = *(const short8*)(XP + kt * n32 + ro2);
        }

        f32x4 acc[8];
        #pragma unroll
        for (int m = 0; m < 8; m++) acc[m] = (f32x4){0.f, 0.f, 0.f, 0.f};
        #pragma unroll
        for (int kt = 0; kt < NKT; kt++) {
            #pragma unroll
            for (int m = 0; m < 8; m++) {
                short8 ah = *(const short8*)&w[kt][m * 16 + r][pu8];
                acc[m] = __builtin_amdgcn_mfma_f32_16x16x32_bf16(ah, xc[kt], acc[m], 0, 0, 0);
            }
        }

        int row = tile * 16 + r;
        if (row < n) {
            float di = dinv[row];
            #pragma unroll
            for (int m = 0; m < 8; m++) {
                f32x4 a = acc[m];
                uint2 pk;
                pk.x = (uint)f2bf(a[0] * di) | ((uint)f2bf(a[1] * di) << 16);
                pk.y = (uint)f2bf(a[2] * di) | ((uint)f2bf(a[3] * di) << 16);
                *(uint2*)(g + (size_t)row * HDIM + m * 16 + gq * 4) = pk;
            }
        }

        #pragma unroll
        for (int kt = 0; kt < NKT; kt++) xc[kt] = xn[kt];
        tile = tnext;
    }
}

// ===== gather + finish: o = [relu](dinv*(g[d] + sum g[src]) + b) =====
// EMIT_PLANE: write bf16 activation plane, tile-major [4][n][32], swizzled.

template<bool RELU, bool EMIT_PLANE>
__global__ __launch_bounds__(256) void k_gather(const ushort* __restrict__ g,
                                                const int* __restrict__ csr,
                                                const int* __restrict__ offs,
                                                const float* __restrict__ dinv,
                                                const float* __restrict__ bias,
                                                float* __restrict__ out,
                                                ushort* __restrict__ ap, int n)
{
    int t    = blockIdx.x * 256 + threadIdx.x;
    int node = t >> 5;
    int l    = t & 31;
    if (node >= n) return;

    int e0 = offs[node];
    int e1 = offs[node + 1];

    float4 acc = bf4_to_f4(*(const uint2*)(g + (size_t)node * HDIM + l * 4));

    int e = e0;
    for (; e + 4 <= e1; e += 4) {
        int s0 = csr[e], s1 = csr[e + 1], s2 = csr[e + 2], s3 = csr[e + 3];
        float4 v0 = bf4_to_f4(*(const uint2*)(g + (size_t)s0 * HDIM + l * 4));
        float4 v1 = bf4_to_f4(*(const uint2*)(g + (size_t)s1 * HDIM + l * 4));
        float4 v2 = bf4_to_f4(*(const uint2*)(g + (size_t)s2 * HDIM + l * 4));
        float4 v3 = bf4_to_f4(*(const uint2*)(g + (size_t)s3 * HDIM + l * 4));
        acc.x += v0.x + v1.x + v2.x + v3.x;
        acc.y += v0.y + v1.y + v2.y + v3.y;
        acc.z += v0.z + v1.z + v2.z + v3.z;
        acc.w += v0.w + v1.w + v2.w + v3.w;
    }
    for (; e < e1; e++) {
        int s = csr[e];
        float4 v = bf4_to_f4(*(const uint2*)(g + (size_t)s * HDIM + l * 4));
        acc.x += v.x; acc.y += v.y; acc.z += v.z; acc.w += v.w;
    }

    float di  = dinv[node];
    float4 bb = *(const float4*)(bias + l * 4);
    float4 o;
    o.x = fmaf(di, acc.x, bb.x);
    o.y = fmaf(di, acc.y, bb.y);
    o.z = fmaf(di, acc.z, bb.z);
    o.w = fmaf(di, acc.w, bb.w);
    if (RELU) {
        o.x = fmaxf(o.x, 0.f); o.y = fmaxf(o.y, 0.f);
        o.z = fmaxf(o.z, 0.f); o.w = fmaxf(o.w, 0.f);
    }
    if (EMIT_PLANE) {
        uint2 ph;
        ph.x = (uint)f2bf(o.x) | ((uint)f2bf(o.y) << 16);
        ph.y = (uint)f2bf(o.z) | ((uint)f2bf(o.w) << 16);
        int kt = l >> 3;
        size_t base = (size_t)kt * n * 32 + (size_t)node * 32
                    + (((l & 7) * 4) ^ (((node >> 1) & 3) << 3));
        *(uint2*)(ap + base) = ph;
    } else {
        *(float4*)(out + (size_t)node * HDIM + l * 4) = o;
    }
}

// ======================= launch =======================

extern "C" void kernel_launch(void* const* d_in, const int* in_sizes, int n_in,
                              void* d_out, int out_size, void* d_ws, size_t ws_size,
                              hipStream_t stream)
{
    const float* x  = (const float*)d_in[0];
    const int*   ei = (const int*)d_in[1];
    const float* W1 = (const float*)d_in[2];
    const float* b1 = (const float*)d_in[3];
    const float* W2 = (const float*)d_in[4];
    const float* b2 = (const float*)d_in[5];
    const float* W3 = (const float*)d_in[6];
    const float* b3 = (const float*)d_in[7];
    float* out = (float*)d_out;

    const int n = in_sizes[0] / 256;   // IN = 256
    const int E = in_sizes[1] / 2;
    const int* src = ei;
    const int* dst = ei + E;

    // workspace layout (bytes):
    //   dinv @0, cnt @512K, offs @1M, bsum @1.5M, csr @1600K (6.4MB),
    //   rank @8M (6.4MB), wt @14.5M (128K slot), g @16M (25.7MB),
    //   xp @42M (51.5MB max, K=256)
    char*   ws   = (char*)d_ws;
    float*  dinv = (float*)(ws);
    int*    cnt  = (int*)(ws + (512 << 10));
    int*    offs = (int*)(ws + (1 << 20));
    int*    bsum = (int*)(ws + 1536 * 1024);
    int*    csr  = (int*)(ws + 1600 * 1024);
    int*    rank = (int*)(ws + (size_t)(8 << 20));
    ushort* wt   = (ushort*)(ws + 14848 * 1024);
    ushort* g    = (ushort*)(ws + (size_t)(16 << 20));
    ushort* xp   = (ushort*)(ws + (size_t)(42 << 20));

    dim3 blk(256);
    int ngrid = (n + 255) / 256;
    int egrid = (E + 255) / 256;

    // ---- CSR build + norms ----
    hipMemsetAsync(cnt, 0, (size_t)n * 4, stream);
    k_count<<<egrid, blk, 0, stream>>>(dst, cnt, rank, E);
    k_dinv<<<ngrid, blk, 0, stream>>>(cnt, dinv, n);
    k_scan1<<<ngrid, blk, 0, stream>>>(cnt, offs, bsum, n);
    k_scan2<<<1, 512, 0, stream>>>(bsum, ngrid);
    k_scan3<<<ngrid, blk, 0, stream>>>(offs, bsum, n, E);
    k_fill<<<egrid, blk, 0, stream>>>(src, dst, offs, rank, csr, E);

    int gat_grid = (int)(((size_t)n * 32 + 255) / 256);
    const int MMB8 = 512;    // grid for K=256 mm (64KB LDS, 2 blocks/CU)
    const int MMB4 = 768;    // grid for K=128 mm (32KB LDS, 3 blocks/CU)

    // layer 1 (K=256)
    k_prep_w<<<(256 * HDIM + 255) / 256, blk, 0, stream>>>(W1, wt, 256);
    {
        dim3 sg((n * 4 + 255) / 256, 8);
        k_split_x<<<sg, blk, 0, stream>>>(x, xp, n);
    }
    k_mm<8><<<MMB8, 512, 0, stream>>>(xp, wt, dinv, g, n, MMB8);
    k_gather<true, true><<<gat_grid, blk, 0, stream>>>(g, csr, offs, dinv, b1, nullptr, xp, n);
    // layer 2 (K=128; xp now holds the [4][n][32] activation plane)
    k_prep_w<<<(128 * HDIM + 255) / 256, blk, 0, stream>>>(W2, wt, 128);
    k_mm<4><<<MMB4, 512, 0, stream>>>(xp, wt, dinv, g, n, MMB4);
    k_gather<true, true><<<gat_grid, blk, 0, stream>>>(g, csr, offs, dinv, b2, nullptr, xp, n);
    // layer 3 (K=128)
    k_prep_w<<<(128 * HDIM + 255) / 256, blk, 0, stream>>>(W3, wt, 128);
    k_mm<4><<<MMB4, 512, 0, stream>>>(xp, wt, dinv, g, n, MMB4);
    k_gather<false, false><<<gat_grid, blk, 0, stream>>>(g, csr, offs, dinv, b3, out, nullptr, n);
}